// Round 4
// baseline (425.791 us; speedup 1.0000x reference)
//
#include <hip/hip_runtime.h>
#include <math.h>

// Relational Network fused pipeline for MI355X (gfx950).
// B=32, D=64, K=26, QST=256, G=[512x6, 28], AGG at layer 4.
//
// Round 9 changes vs round 8:
//  - Round 8's B ping-pong re-spilled (WRITE 233MB): acc[4][4] pins 64 AGPRs
//    of the 128 unified budget -> only 64 arch VGPRs; bfr+bfrN=32 B-regs
//    structurally live blew it. New inner loop keeps prefetch but caps
//    pressure: j-OUTER clusters with ROLLING B (cluster j consumes b[j],
//    then b[j] is reloaded with step s+1's fragment; only 16 B regs live;
//    sched_barrier(0) after each cluster pins MFMA-before-reload order so
//    the scheduler can't hoist loads and recreate the double buffer), plus
//    A even/odd double-buffer across steps (32 regs). Live ~60 <= 64 arch.
//  - Keeps round 8's per-block partials P (no atomics) and 1024-thread
//    k_tail (2-way k-split layers 4/5).

typedef __attribute__((ext_vector_type(8))) short bf16x8;   // 8 bf16 in 4 VGPRs
typedef __attribute__((ext_vector_type(4))) float f32x4;    // MFMA 16x16 accumulator
typedef __attribute__((ext_vector_type(4))) unsigned int u32x4;

__device__ __forceinline__ unsigned short f2bf(float f) {
    union { float f; unsigned u; } x; x.f = f;
    unsigned r = x.u + 0x7fffu + ((x.u >> 16) & 1u);   // RNE
    return (unsigned short)(r >> 16);
}

// ---------------- pack / transpose weights ----------------
// Wp layout per layer: [wave(8)][s(16)][jj(4)][lane(64)][j(8)] bf16,
//   value = W[n][k], n = (wave*4+jj)*16 + (lane&15), k = s*32 + (lane>>4)*8 + j.
// W0p: same with s(2) over padded K=64 (k >= 52 -> 0).
// W4v/W5v: fp32 [k/4][512 out][4] so k_tail threads stream float4.
#define NP_WP   786432            // 3 * 512*512
#define NP_W0P  32768             // 512*64 (K padded 52->64)
#define NP_W4T  393216            // 512*768
#define NP_W5T  262144            // 512*512
#define NP_TOTAL (NP_WP + NP_W0P + NP_W4T + NP_W5T)   // 1474560 = 5760*256
__global__ void k_prep(const float* __restrict__ W1, const float* __restrict__ W2,
                       const float* __restrict__ W3, const float* __restrict__ W0,
                       const float* __restrict__ W4, const float* __restrict__ W5,
                       unsigned short* __restrict__ Wp,   // [3][262144] bf16
                       unsigned short* __restrict__ W0p,  // [32768] bf16
                       float* __restrict__ W4v,           // [192][512][4] fp32
                       float* __restrict__ W5v)           // [128][512][4] fp32
{
    int f = blockIdx.x * 256 + threadIdx.x;
    if (f < NP_WP) {
        int l = f >> 18, r = f & 262143;
        int n = r >> 9, k = r & 511;                    // read W[n*512+k] coalesced
        const float* W = (l == 0) ? W1 : (l == 1) ? W2 : W3;
        float v = W[r];
        int wv = n >> 6, jj = (n >> 4) & 3, i16 = n & 15;
        int s = k >> 5, q4 = (k >> 3) & 3, j = k & 7;
        int lane = q4 * 16 + i16;
        Wp[(size_t)l * 262144 + ((((wv * 16 + s) * 4 + jj) * 64 + lane) << 3) + j] = f2bf(v);
    } else if (f < NP_WP + NP_W0P) {
        int g = f - NP_WP;
        int n = g >> 6, k = g & 63;
        float v = (k < 52) ? W0[n * 52 + k] : 0.f;
        int wv = n >> 6, jj = (n >> 4) & 3, i16 = n & 15;
        int s = k >> 5, q4 = (k >> 3) & 3, j = k & 7;
        int lane = q4 * 16 + i16;
        W0p[((((wv * 2 + s) * 4 + jj) * 64 + lane) << 3) + j] = f2bf(v);
    } else if (f < NP_WP + NP_W0P + NP_W4T) {
        int g = f - (NP_WP + NP_W0P);
        int o = g / 768, k = g % 768;                   // read W4[g] coalesced
        W4v[(size_t)((k >> 2) * 512 + o) * 4 + (k & 3)] = W4[g];
    } else {
        int g = f - (NP_WP + NP_W0P + NP_W4T);
        int o = g >> 9, k = g & 511;                    // read W5[g] coalesced
        W5v[(size_t)((k >> 2) * 512 + o) * 4 + (k & 3)] = W5[g];
    }
}

// ---------------- h-store epilogue: bias + relu + bf16 LDS write ----
// Granule-column-major target: byte = (col>>3)*1024 + (row ^ ((col>>3)&7))*16
//                                    + (col&7)*2.
// Packs (col, col+1) via DPP quad_perm; even lanes write ds_write_b32.
__device__ __forceinline__ void store_h(const f32x4 (&acc)[4][4], const float* __restrict__ bl,
                                        unsigned short* hsm, int wave, int i16, int q4, int lane)
{
    char* base = (char*)hsm;
    #pragma unroll
    for (int j = 0; j < 4; ++j) {
        int col = (wave * 4 + j) * 16 + i16;
        int g = col >> 3;
        int e = g & 7;
        float bb = bl[col];
        #pragma unroll
        for (int mt = 0; mt < 4; ++mt) {
            #pragma unroll
            for (int r = 0; r < 4; ++r) {
                int row = mt * 16 + q4 * 4 + r;
                float v = fmaxf(acc[mt][j][r] + bb, 0.f);
                unsigned hv = f2bf(v);
                // quad_perm [1,0,3,2]: each lane gets partner (lane^1)'s value
                unsigned sw = (unsigned)__builtin_amdgcn_update_dpp(0, (int)hv, 0xB1, 0xF, 0xF, true);
                if ((lane & 1) == 0) {
                    int slot = row ^ e;
                    *(unsigned*)(base + g * 1024 + slot * 16 + ((col & 7) << 1)) = hv | (sw << 16);
                }
            }
        }
    }
}

#define CLUSTER(AV0, AV1, AV2, AV3, BV, JJ)                                              \
    __builtin_amdgcn_s_setprio(1);                                                      \
    acc[0][JJ] = __builtin_amdgcn_mfma_f32_16x16x32_bf16(AV0, BV, acc[0][JJ], 0, 0, 0); \
    acc[1][JJ] = __builtin_amdgcn_mfma_f32_16x16x32_bf16(AV1, BV, acc[1][JJ], 0, 0, 0); \
    acc[2][JJ] = __builtin_amdgcn_mfma_f32_16x16x32_bf16(AV2, BV, acc[2][JJ], 0, 0, 0); \
    acc[3][JJ] = __builtin_amdgcn_mfma_f32_16x16x32_bf16(AV3, BV, acc[3][JJ], 0, 0, 0); \
    __builtin_amdgcn_s_setprio(0);                                                      \
    __builtin_amdgcn_sched_barrier(0);

// ---------------- fused layers 0..3 ----------------
// One block per (b,p): 64 pair-rows. h tile 64x512 bf16 in LDS,
// granule-column-major: hsm[g=k>>3][slot=row^(g&7)][8 shorts].
// 8 waves; wave w computes cols [w*64, w*64+64): acc = 4 (row tiles) x 4 (col tiles).
__global__ __launch_bounds__(512, 4) void k_fused(
    const float* __restrict__ x,
    const unsigned short* __restrict__ Wp,
    const unsigned short* __restrict__ W0p,
    const float* __restrict__ b0, const float* __restrict__ b1,
    const float* __restrict__ b2, const float* __restrict__ b3,
    float* __restrict__ P)
{
    __shared__ __align__(16) unsigned short hsm[64 * 512];   // 64 KiB
    __shared__ __align__(16) unsigned short xs[8 * 64 * 8];  // 8 KiB (x-pair tile)
    int t = threadIdx.x;
    int blk = blockIdx.x;
    int b = blk >> 6, p = blk & 63;

    // ---- stage xs: [g(8)][slot=row^g][8] bf16 of [x[b,row,:26] | x[b,p,:26] | 0] ----
    {
        int row = t >> 3, gr = t & 7;
        const float* xq = x + (size_t)(b * 64 + row) * 26;
        const float* xp = x + (size_t)(b * 64 + p) * 26;
        unsigned w[4];
        #pragma unroll
        for (int h = 0; h < 4; ++h) {
            int k0 = gr * 8 + h * 2;
            int k1 = k0 + 1;
            float f0 = (k0 < 26) ? xq[k0] : (k0 < 52 ? xp[k0 - 26] : 0.f);
            float f1 = (k1 < 26) ? xq[k1] : (k1 < 52 ? xp[k1 - 26] : 0.f);
            w[h] = (unsigned)f2bf(f0) | ((unsigned)f2bf(f1) << 16);
        }
        *(u32x4*)((char*)xs + gr * 1024 + ((row ^ gr) << 4)) = (u32x4){w[0], w[1], w[2], w[3]};
    }

    int wave = t >> 6, lane = t & 63;
    int i16 = lane & 15, q4 = lane >> 4;

    f32x4 acc[4][4];

    __syncthreads();   // xs ready

    // ---- layer 0: h0 = relu([x_q|x_p] @ W0^T + b0), K=64 padded ----
    {
        #pragma unroll
        for (int mt = 0; mt < 4; ++mt)
            #pragma unroll
            for (int j = 0; j < 4; ++j)
                acc[mt][j] = (f32x4){0.f, 0.f, 0.f, 0.f};
        const unsigned short* Bb0 = W0p + wave * 4096 + lane * 8;
        const char* xb = (const char*)xs;
        #pragma unroll
        for (int s = 0; s < 2; ++s) {
            bf16x8 bfr[4];
            #pragma unroll
            for (int j = 0; j < 4; ++j)
                bfr[j] = *(const bf16x8*)(Bb0 + s * 2048 + j * 512);
            int g = s * 4 + q4;
            const char* A0 = xb + g * 1024 + ((i16 ^ g) << 4);
            #pragma unroll
            for (int mt = 0; mt < 4; ++mt) {
                bf16x8 a = *(const bf16x8*)(A0 + mt * 256);
                #pragma unroll
                for (int j = 0; j < 4; ++j)
                    acc[mt][j] = __builtin_amdgcn_mfma_f32_16x16x32_bf16(a, bfr[j], acc[mt][j], 0, 0, 0);
            }
        }
        store_h(acc, b0, hsm, wave, i16, q4, lane);   // each wave writes its own cols
    }

    // ---- layers 1..3: j-outer clusters, rolling-B prefetch, A even/odd dbuf ----
    // A byte addr for step s: hb + s*4096 + A_base(s&1) + mt*256.
    int A_even = (q4 << 10) + ((i16 ^ q4) << 4);
    int A_odd  = A_even ^ 64;
    const char* hbe = (const char*)hsm + A_even;          // even-step A base
    const char* hbo = (const char*)hsm + 4096 + A_odd;    // odd-step A base

    #pragma unroll 1
    for (int l = 0; l < 3; ++l) {
        const float* bl = (l == 0) ? b1 : (l == 1) ? b2 : b3;
        // B fragments: one shared per-lane address; j at +1024B, s at +4096B.
        const unsigned short* Bb = Wp + (size_t)l * 262144 + wave * 32768 + lane * 8;

        // step-0 B rides the barrier
        bf16x8 b0v = *(const bf16x8*)(Bb);
        bf16x8 b1v = *(const bf16x8*)(Bb + 512);
        bf16x8 b2v = *(const bf16x8*)(Bb + 1024);
        bf16x8 b3v = *(const bf16x8*)(Bb + 1536);

        __syncthreads();   // h ready

        #pragma unroll
        for (int mt = 0; mt < 4; ++mt)
            #pragma unroll
            for (int j = 0; j < 4; ++j)
                acc[mt][j] = (f32x4){0.f, 0.f, 0.f, 0.f};

        // step-0 A
        bf16x8 aE0 = *(const bf16x8*)(hbe);
        bf16x8 aE1 = *(const bf16x8*)(hbe + 256);
        bf16x8 aE2 = *(const bf16x8*)(hbe + 512);
        bf16x8 aE3 = *(const bf16x8*)(hbe + 768);
        bf16x8 aO0, aO1, aO2, aO3;

        #pragma unroll 1
        for (int s = 0; s < 16; s += 2) {
            // ===== even step s: consume aE*, b*v; prefetch aO*(s+1), B(s+1) =====
            {
                const unsigned short* Bs = Bb + (s + 1) * 2048;
                const char* po = hbo + (s << 12);          // A for s+1
                CLUSTER(aE0, aE1, aE2, aE3, b0v, 0)
                b0v = *(const bf16x8*)(Bs);
                aO0 = *(const bf16x8*)(po);
                CLUSTER(aE0, aE1, aE2, aE3, b1v, 1)
                b1v = *(const bf16x8*)(Bs + 512);
                aO1 = *(const bf16x8*)(po + 256);
                CLUSTER(aE0, aE1, aE2, aE3, b2v, 2)
                b2v = *(const bf16x8*)(Bs + 1024);
                aO2 = *(const bf16x8*)(po + 512);
                CLUSTER(aE0, aE1, aE2, aE3, b3v, 3)
                b3v = *(const bf16x8*)(Bs + 1536);
                aO3 = *(const bf16x8*)(po + 768);
            }
            // ===== odd step s+1: consume aO*, b*v; prefetch aE*(s+2), B(s+2) =====
            {
                int s2 = (s + 2 < 16) ? (s + 2) : 14;      // tail dummy reload (unused)
                const unsigned short* Bs = Bb + s2 * 2048;
                const char* pe = hbe + (s2 << 12);         // A for s+2 (clamped dummy)
                CLUSTER(aO0, aO1, aO2, aO3, b0v, 0)
                b0v = *(const bf16x8*)(Bs);
                aE0 = *(const bf16x8*)(pe);
                CLUSTER(aO0, aO1, aO2, aO3, b1v, 1)
                b1v = *(const bf16x8*)(Bs + 512);
                aE1 = *(const bf16x8*)(pe + 256);
                CLUSTER(aO0, aO1, aO2, aO3, b2v, 2)
                b2v = *(const bf16x8*)(Bs + 1024);
                aE2 = *(const bf16x8*)(pe + 512);
                CLUSTER(aO0, aO1, aO2, aO3, b3v, 3)
                b3v = *(const bf16x8*)(Bs + 1536);
                aE3 = *(const bf16x8*)(pe + 768);
            }
        }
        __syncthreads();   // all reads of h done before overwrite

        if (l < 2) {
            store_h(acc, bl, hsm, wave, i16, q4, lane);
        } else {
            // layer 3: bias + relu + sum over 64 rows -> per-block partial P[blk][col]
            #pragma unroll
            for (int j = 0; j < 4; ++j) {
                int col = (wave * 4 + j) * 16 + i16;
                float bb = bl[col];
                float sum = 0.f;
                #pragma unroll
                for (int mt = 0; mt < 4; ++mt)
                    #pragma unroll
                    for (int r = 0; r < 4; ++r)
                        sum += fmaxf(acc[mt][j][r] + bb, 0.f);
                sum += __shfl_xor(sum, 16);
                sum += __shfl_xor(sum, 32);
                if (q4 == 0) P[(size_t)blk * 512 + col] = sum;
            }
        }
    }
}

// ---------------- tail: reduce P + layers 4,5,6 + log_softmax ----
__global__ __launch_bounds__(1024) void k_tail(
    const float* __restrict__ P, const float* __restrict__ qst,
    const float* __restrict__ W4v, const float* __restrict__ b4,
    const float* __restrict__ W5v, const float* __restrict__ b5,
    const float* __restrict__ W6, const float* __restrict__ b6,
    float* __restrict__ out)
{
    int b = blockIdx.x, t = threadIdx.x;
    __shared__ __align__(16) float z[768];
    __shared__ __align__(16) float ps[1024];
    __shared__ __align__(16) float h4[512];
    __shared__ float h5[512];
    __shared__ float logits[28];
    __shared__ float red[2];

    if (t < 512) {     // reduce the 64 per-(b,p)-block partials
        float s = 0.f;
        const float* Pb = P + (size_t)b * 64 * 512 + t;
        #pragma unroll 8
        for (int c = 0; c < 64; ++c) s += Pb[c * 512];
        z[t] = s;
    } else if (t < 768) {
        z[t] = qst[b * 256 + (t - 512)];
    }
    __syncthreads();
    {   // layer 4: 768 -> 512, 2-way k-split per output
        int o = t & 511, hf = t >> 9;
        float acc = 0.f;
        const float4* Wv = (const float4*)W4v;
        const float4* z4 = (const float4*)z;
        #pragma unroll 4
        for (int kb = hf * 96; kb < hf * 96 + 96; ++kb) {
            float4 w = Wv[kb * 512 + o];
            float4 zz = z4[kb];
            acc = fmaf(w.x, zz.x, acc);
            acc = fmaf(w.y, zz.y, acc);
            acc = fmaf(w.z, zz.z, acc);
            acc = fmaf(w.w, zz.w, acc);
        }
        ps[t] = acc;
    }
    __syncthreads();
    if (t < 512) h4[t] = fmaxf(ps[t] + ps[t + 512] + b4[t], 0.f);
    __syncthreads();
    {   // layer 5: 512 -> 512, 2-way k-split per output
        int o = t & 511, hf = t >> 9;
        float acc = 0.f;
        const float4* Wv = (const float4*)W5v;
        const float4* h44 = (const float4*)h4;
        #pragma unroll 4
        for (int kb = hf * 64; kb < hf * 64 + 64; ++kb) {
            float4 w = Wv[kb * 512 + o];
            float4 hh = h44[kb];
            acc = fmaf(w.x, hh.x, acc);
            acc = fmaf(w.y, hh.y, acc);
            acc = fmaf(w.z, hh.z, acc);
            acc = fmaf(w.w, hh.w, acc);
        }
        ps[t] = acc;
    }
    __syncthreads();
    if (t < 512) h5[t] = fmaxf(ps[t] + ps[t + 512] + b5[t], 0.f);
    __syncthreads();
    {   // layer 6: 512 -> 28 (32 lanes per output)
        int o = t >> 5, c = t & 31;
        if (o < 28) {
            float acc = 0.f;
            for (int k = c; k < 512; k += 32) acc = fmaf(W6[o * 512 + k], h5[k], acc);
            acc += __shfl_xor(acc, 1);
            acc += __shfl_xor(acc, 2);
            acc += __shfl_xor(acc, 4);
            acc += __shfl_xor(acc, 8);
            acc += __shfl_xor(acc, 16);
            if (c == 0) logits[o] = acc + b6[o];
        }
    }
    __syncthreads();
    if (t == 0) {
        float mx = -1e30f;
        for (int cc = 0; cc < 28; ++cc) mx = fmaxf(mx, logits[cc]);
        float se = 0.f;
        for (int cc = 0; cc < 28; ++cc) se += expf(logits[cc] - mx);
        red[0] = mx; red[1] = logf(se);
    }
    __syncthreads();
    if (t < 28) out[b * 28 + t] = logits[t] - red[0] - red[1];
}

extern "C" void kernel_launch(void* const* d_in, const int* in_sizes, int n_in,
                              void* d_out, int out_size, void* d_ws, size_t ws_size,
                              hipStream_t stream)
{
    const float* x   = (const float*)d_in[0];
    const float* qst = (const float*)d_in[1];
    const float* W0  = (const float*)d_in[2];
    const float* b0  = (const float*)d_in[3];
    const float* W1  = (const float*)d_in[4];
    const float* b1  = (const float*)d_in[5];
    const float* W2  = (const float*)d_in[6];
    const float* b2  = (const float*)d_in[7];
    const float* W3  = (const float*)d_in[8];
    const float* b3  = (const float*)d_in[9];
    const float* W4  = (const float*)d_in[10];
    const float* b4  = (const float*)d_in[11];
    const float* W5  = (const float*)d_in[12];
    const float* b5  = (const float*)d_in[13];
    const float* W6  = (const float*)d_in[14];
    const float* b6  = (const float*)d_in[15];
    float* out = (float*)d_out;

    char* ws = (char*)d_ws;
    unsigned short* Wp  = (unsigned short*)(ws);             // 1.5 MiB
    unsigned short* W0p = (unsigned short*)(ws + 1572864);   // 64 KiB
    float*          W4v = (float*)(ws + 1638400);            // 1.5 MiB
    float*          W5v = (float*)(ws + 3211264);            // 1 MiB
    float*          P   = (float*)(ws + 4259840);            // 4 MiB partials

    k_prep <<<NP_TOTAL / 256, 256, 0, stream>>>(W1, W2, W3, W0, W4, W5,
                                                Wp, W0p, W4v, W5v);
    k_fused<<<2048, 512, 0, stream>>>(x, Wp, W0p, b0, b1, b2, b3, P);
    k_tail <<<32, 1024, 0, stream>>>(P, qst, W4v, b4, W5v, b5, W6, b6, out);
}

// Round 5
// 324.926 us; speedup vs baseline: 1.3104x; 1.3104x over previous
//
#include <hip/hip_runtime.h>
#include <math.h>

// Relational Network fused pipeline for MI355X (gfx950).
// B=32, D=64, K=26, QST=256, G=[512x6, 28], AGG at layer 4.
//
// Round 10 changes vs round 9:
//  - ROOT CAUSE of rounds 6/8/9 spills: launch_bounds(512,4) caps the
//    unified file at 128/wave while acc[4][4] pins 64 AGPRs -> every
//    pipeline attempt spilled ~200B/thread. But LDS (72KiB) already limits
//    us to <=2 blocks/CU, and the HK-proven GEMM point is 1 block x 8 waves
//    at ~256 VGPR with a deep register pipeline. So: launch_bounds(512,2)
//    -> 256 unified regs/wave, 1 block/CU.
//  - Inner loop now affordable: full B double-buffer X/Y with TWO-step-ahead
//    reload (each fragment reloaded right after last use; load->use ~2
//    k-steps > L2 latency) + A even/odd LDS dbuf (1 step ahead > LDS
//    latency). Structural live ~150 regs < 256: no spill by construction.
//  - Keeps per-block partials P (no atomics) and 1024-thread k_tail.

typedef __attribute__((ext_vector_type(8))) short bf16x8;   // 8 bf16 in 4 VGPRs
typedef __attribute__((ext_vector_type(4))) float f32x4;    // MFMA 16x16 accumulator
typedef __attribute__((ext_vector_type(4))) unsigned int u32x4;

__device__ __forceinline__ unsigned short f2bf(float f) {
    union { float f; unsigned u; } x; x.f = f;
    unsigned r = x.u + 0x7fffu + ((x.u >> 16) & 1u);   // RNE
    return (unsigned short)(r >> 16);
}

// ---------------- pack / transpose weights ----------------
// Wp layout per layer: [wave(8)][s(16)][jj(4)][lane(64)][j(8)] bf16,
//   value = W[n][k], n = (wave*4+jj)*16 + (lane&15), k = s*32 + (lane>>4)*8 + j.
// W0p: same with s(2) over padded K=64 (k >= 52 -> 0).
// W4v/W5v: fp32 [k/4][512 out][4] so k_tail threads stream float4.
#define NP_WP   786432            // 3 * 512*512
#define NP_W0P  32768             // 512*64 (K padded 52->64)
#define NP_W4T  393216            // 512*768
#define NP_W5T  262144            // 512*512
#define NP_TOTAL (NP_WP + NP_W0P + NP_W4T + NP_W5T)   // 1474560 = 5760*256
__global__ void k_prep(const float* __restrict__ W1, const float* __restrict__ W2,
                       const float* __restrict__ W3, const float* __restrict__ W0,
                       const float* __restrict__ W4, const float* __restrict__ W5,
                       unsigned short* __restrict__ Wp,   // [3][262144] bf16
                       unsigned short* __restrict__ W0p,  // [32768] bf16
                       float* __restrict__ W4v,           // [192][512][4] fp32
                       float* __restrict__ W5v)           // [128][512][4] fp32
{
    int f = blockIdx.x * 256 + threadIdx.x;
    if (f < NP_WP) {
        int l = f >> 18, r = f & 262143;
        int n = r >> 9, k = r & 511;                    // read W[n*512+k] coalesced
        const float* W = (l == 0) ? W1 : (l == 1) ? W2 : W3;
        float v = W[r];
        int wv = n >> 6, jj = (n >> 4) & 3, i16 = n & 15;
        int s = k >> 5, q4 = (k >> 3) & 3, j = k & 7;
        int lane = q4 * 16 + i16;
        Wp[(size_t)l * 262144 + ((((wv * 16 + s) * 4 + jj) * 64 + lane) << 3) + j] = f2bf(v);
    } else if (f < NP_WP + NP_W0P) {
        int g = f - NP_WP;
        int n = g >> 6, k = g & 63;
        float v = (k < 52) ? W0[n * 52 + k] : 0.f;
        int wv = n >> 6, jj = (n >> 4) & 3, i16 = n & 15;
        int s = k >> 5, q4 = (k >> 3) & 3, j = k & 7;
        int lane = q4 * 16 + i16;
        W0p[((((wv * 2 + s) * 4 + jj) * 64 + lane) << 3) + j] = f2bf(v);
    } else if (f < NP_WP + NP_W0P + NP_W4T) {
        int g = f - (NP_WP + NP_W0P);
        int o = g / 768, k = g % 768;                   // read W4[g] coalesced
        W4v[(size_t)((k >> 2) * 512 + o) * 4 + (k & 3)] = W4[g];
    } else {
        int g = f - (NP_WP + NP_W0P + NP_W4T);
        int o = g >> 9, k = g & 511;                    // read W5[g] coalesced
        W5v[(size_t)((k >> 2) * 512 + o) * 4 + (k & 3)] = W5[g];
    }
}

// ---------------- h-store epilogue: bias + relu + bf16 LDS write ----
// Granule-column-major target: byte = (col>>3)*1024 + (row ^ ((col>>3)&7))*16
//                                    + (col&7)*2.
// Packs (col, col+1) via DPP quad_perm; even lanes write ds_write_b32.
__device__ __forceinline__ void store_h(const f32x4 (&acc)[4][4], const float* __restrict__ bl,
                                        unsigned short* hsm, int wave, int i16, int q4, int lane)
{
    char* base = (char*)hsm;
    #pragma unroll
    for (int j = 0; j < 4; ++j) {
        int col = (wave * 4 + j) * 16 + i16;
        int g = col >> 3;
        int e = g & 7;
        float bb = bl[col];
        #pragma unroll
        for (int mt = 0; mt < 4; ++mt) {
            #pragma unroll
            for (int r = 0; r < 4; ++r) {
                int row = mt * 16 + q4 * 4 + r;
                float v = fmaxf(acc[mt][j][r] + bb, 0.f);
                unsigned hv = f2bf(v);
                // quad_perm [1,0,3,2]: each lane gets partner (lane^1)'s value
                unsigned sw = (unsigned)__builtin_amdgcn_update_dpp(0, (int)hv, 0xB1, 0xF, 0xF, true);
                if ((lane & 1) == 0) {
                    int slot = row ^ e;
                    *(unsigned*)(base + g * 1024 + slot * 16 + ((col & 7) << 1)) = hv | (sw << 16);
                }
            }
        }
    }
}

#define CLUSTER(AV0, AV1, AV2, AV3, BV, JJ)                                              \
    __builtin_amdgcn_s_setprio(1);                                                      \
    acc[0][JJ] = __builtin_amdgcn_mfma_f32_16x16x32_bf16(AV0, BV, acc[0][JJ], 0, 0, 0); \
    acc[1][JJ] = __builtin_amdgcn_mfma_f32_16x16x32_bf16(AV1, BV, acc[1][JJ], 0, 0, 0); \
    acc[2][JJ] = __builtin_amdgcn_mfma_f32_16x16x32_bf16(AV2, BV, acc[2][JJ], 0, 0, 0); \
    acc[3][JJ] = __builtin_amdgcn_mfma_f32_16x16x32_bf16(AV3, BV, acc[3][JJ], 0, 0, 0); \
    __builtin_amdgcn_s_setprio(0);                                                      \
    __builtin_amdgcn_sched_barrier(0);

// ---------------- fused layers 0..3 ----------------
// One block per (b,p): 64 pair-rows. h tile 64x512 bf16 in LDS,
// granule-column-major: hsm[g=k>>3][slot=row^(g&7)][8 shorts].
// 8 waves; wave w computes cols [w*64, w*64+64): acc = 4 (row tiles) x 4 (col tiles).
__global__ __launch_bounds__(512, 2) void k_fused(
    const float* __restrict__ x,
    const unsigned short* __restrict__ Wp,
    const unsigned short* __restrict__ W0p,
    const float* __restrict__ b0, const float* __restrict__ b1,
    const float* __restrict__ b2, const float* __restrict__ b3,
    float* __restrict__ P)
{
    __shared__ __align__(16) unsigned short hsm[64 * 512];   // 64 KiB
    __shared__ __align__(16) unsigned short xs[8 * 64 * 8];  // 8 KiB (x-pair tile)
    int t = threadIdx.x;
    int blk = blockIdx.x;
    int b = blk >> 6, p = blk & 63;

    // ---- stage xs: [g(8)][slot=row^g][8] bf16 of [x[b,row,:26] | x[b,p,:26] | 0] ----
    {
        int row = t >> 3, gr = t & 7;
        const float* xq = x + (size_t)(b * 64 + row) * 26;
        const float* xp = x + (size_t)(b * 64 + p) * 26;
        unsigned w[4];
        #pragma unroll
        for (int h = 0; h < 4; ++h) {
            int k0 = gr * 8 + h * 2;
            int k1 = k0 + 1;
            float f0 = (k0 < 26) ? xq[k0] : (k0 < 52 ? xp[k0 - 26] : 0.f);
            float f1 = (k1 < 26) ? xq[k1] : (k1 < 52 ? xp[k1 - 26] : 0.f);
            w[h] = (unsigned)f2bf(f0) | ((unsigned)f2bf(f1) << 16);
        }
        *(u32x4*)((char*)xs + gr * 1024 + ((row ^ gr) << 4)) = (u32x4){w[0], w[1], w[2], w[3]};
    }

    int wave = t >> 6, lane = t & 63;
    int i16 = lane & 15, q4 = lane >> 4;

    f32x4 acc[4][4];

    __syncthreads();   // xs ready

    // ---- layer 0: h0 = relu([x_q|x_p] @ W0^T + b0), K=64 padded ----
    {
        #pragma unroll
        for (int mt = 0; mt < 4; ++mt)
            #pragma unroll
            for (int j = 0; j < 4; ++j)
                acc[mt][j] = (f32x4){0.f, 0.f, 0.f, 0.f};
        const unsigned short* Bb0 = W0p + wave * 4096 + lane * 8;
        const char* xb = (const char*)xs;
        #pragma unroll
        for (int s = 0; s < 2; ++s) {
            bf16x8 bfr[4];
            #pragma unroll
            for (int j = 0; j < 4; ++j)
                bfr[j] = *(const bf16x8*)(Bb0 + s * 2048 + j * 512);
            int g = s * 4 + q4;
            const char* A0 = xb + g * 1024 + ((i16 ^ g) << 4);
            #pragma unroll
            for (int mt = 0; mt < 4; ++mt) {
                bf16x8 a = *(const bf16x8*)(A0 + mt * 256);
                #pragma unroll
                for (int j = 0; j < 4; ++j)
                    acc[mt][j] = __builtin_amdgcn_mfma_f32_16x16x32_bf16(a, bfr[j], acc[mt][j], 0, 0, 0);
            }
        }
        store_h(acc, b0, hsm, wave, i16, q4, lane);   // each wave writes its own cols
    }

    // ---- layers 1..3: X/Y B-dbuf (2-step-ahead), A even/odd dbuf (1 ahead) ----
    // A byte addr for step s: hsm + s*4096 + A_base(s&1) + mt*256.
    int A_even = (q4 << 10) + ((i16 ^ q4) << 4);
    const char* hbe = (const char*)hsm + A_even;              // even-step A base
    const char* hbo = (const char*)hsm + 4096 + (A_even ^ 64); // odd-step A base

    #pragma unroll 1
    for (int l = 0; l < 3; ++l) {
        const float* bl = (l == 0) ? b1 : (l == 1) ? b2 : b3;
        // B fragments: one shared per-lane address; j at +1024B, s at +4096B.
        const unsigned short* Bb = Wp + (size_t)l * 262144 + wave * 32768 + lane * 8;

        // prefetch B(0) -> X, B(1) -> Y; these ride the barrier drain
        bf16x8 X0 = *(const bf16x8*)(Bb);
        bf16x8 X1 = *(const bf16x8*)(Bb + 512);
        bf16x8 X2 = *(const bf16x8*)(Bb + 1024);
        bf16x8 X3 = *(const bf16x8*)(Bb + 1536);
        bf16x8 Y0 = *(const bf16x8*)(Bb + 2048);
        bf16x8 Y1 = *(const bf16x8*)(Bb + 2560);
        bf16x8 Y2 = *(const bf16x8*)(Bb + 3072);
        bf16x8 Y3 = *(const bf16x8*)(Bb + 3584);

        __syncthreads();   // h ready

        #pragma unroll
        for (int mt = 0; mt < 4; ++mt)
            #pragma unroll
            for (int j = 0; j < 4; ++j)
                acc[mt][j] = (f32x4){0.f, 0.f, 0.f, 0.f};

        // A(0)
        bf16x8 aE0 = *(const bf16x8*)(hbe);
        bf16x8 aE1 = *(const bf16x8*)(hbe + 256);
        bf16x8 aE2 = *(const bf16x8*)(hbe + 512);
        bf16x8 aE3 = *(const bf16x8*)(hbe + 768);
        bf16x8 aO0, aO1, aO2, aO3;

        #pragma unroll 1
        for (int s = 0; s < 16; s += 2) {
            // ===== even step s: consume aE*, X*; reload X = B(s+2), aO = A(s+1) =====
            {
                const unsigned short* BX = Bb + ((s + 2 < 16) ? (s + 2) : 14) * 2048;
                const char* po = hbo + (s << 12);      // A(s+1)
                CLUSTER(aE0, aE1, aE2, aE3, X0, 0)
                X0 = *(const bf16x8*)(BX);
                aO0 = *(const bf16x8*)(po);
                aO1 = *(const bf16x8*)(po + 256);
                CLUSTER(aE0, aE1, aE2, aE3, X1, 1)
                X1 = *(const bf16x8*)(BX + 512);
                aO2 = *(const bf16x8*)(po + 512);
                aO3 = *(const bf16x8*)(po + 768);
                CLUSTER(aE0, aE1, aE2, aE3, X2, 2)
                X2 = *(const bf16x8*)(BX + 1024);
                CLUSTER(aE0, aE1, aE2, aE3, X3, 3)
                X3 = *(const bf16x8*)(BX + 1536);
            }
            // ===== odd step s+1: consume aO*, Y*; reload Y = B(s+3), aE = A(s+2) =====
            {
                const unsigned short* BY = Bb + ((s + 3 < 16) ? (s + 3) : 15) * 2048;
                const char* pe = hbe + ((s + 2 < 16 ? s + 2 : 14) << 12);   // A(s+2)
                CLUSTER(aO0, aO1, aO2, aO3, Y0, 0)
                Y0 = *(const bf16x8*)(BY);
                aE0 = *(const bf16x8*)(pe);
                aE1 = *(const bf16x8*)(pe + 256);
                CLUSTER(aO0, aO1, aO2, aO3, Y1, 1)
                Y1 = *(const bf16x8*)(BY + 512);
                aE2 = *(const bf16x8*)(pe + 512);
                aE3 = *(const bf16x8*)(pe + 768);
                CLUSTER(aO0, aO1, aO2, aO3, Y2, 2)
                Y2 = *(const bf16x8*)(BY + 1024);
                CLUSTER(aO0, aO1, aO2, aO3, Y3, 3)
                Y3 = *(const bf16x8*)(BY + 1536);
            }
        }
        __syncthreads();   // all reads of h done before overwrite

        if (l < 2) {
            store_h(acc, bl, hsm, wave, i16, q4, lane);
        } else {
            // layer 3: bias + relu + sum over 64 rows -> per-block partial P[blk][col]
            #pragma unroll
            for (int j = 0; j < 4; ++j) {
                int col = (wave * 4 + j) * 16 + i16;
                float bb = bl[col];
                float sum = 0.f;
                #pragma unroll
                for (int mt = 0; mt < 4; ++mt)
                    #pragma unroll
                    for (int r = 0; r < 4; ++r)
                        sum += fmaxf(acc[mt][j][r] + bb, 0.f);
                sum += __shfl_xor(sum, 16);
                sum += __shfl_xor(sum, 32);
                if (q4 == 0) P[(size_t)blk * 512 + col] = sum;
            }
        }
    }
}

// ---------------- tail: reduce P + layers 4,5,6 + log_softmax ----
__global__ __launch_bounds__(1024) void k_tail(
    const float* __restrict__ P, const float* __restrict__ qst,
    const float* __restrict__ W4v, const float* __restrict__ b4,
    const float* __restrict__ W5v, const float* __restrict__ b5,
    const float* __restrict__ W6, const float* __restrict__ b6,
    float* __restrict__ out)
{
    int b = blockIdx.x, t = threadIdx.x;
    __shared__ __align__(16) float z[768];
    __shared__ __align__(16) float ps[1024];
    __shared__ __align__(16) float h4[512];
    __shared__ float h5[512];
    __shared__ float logits[28];
    __shared__ float red[2];

    if (t < 512) {     // reduce the 64 per-(b,p)-block partials
        float s = 0.f;
        const float* Pb = P + (size_t)b * 64 * 512 + t;
        #pragma unroll 8
        for (int c = 0; c < 64; ++c) s += Pb[c * 512];
        z[t] = s;
    } else if (t < 768) {
        z[t] = qst[b * 256 + (t - 512)];
    }
    __syncthreads();
    {   // layer 4: 768 -> 512, 2-way k-split per output
        int o = t & 511, hf = t >> 9;
        float acc = 0.f;
        const float4* Wv = (const float4*)W4v;
        const float4* z4 = (const float4*)z;
        #pragma unroll 4
        for (int kb = hf * 96; kb < hf * 96 + 96; ++kb) {
            float4 w = Wv[kb * 512 + o];
            float4 zz = z4[kb];
            acc = fmaf(w.x, zz.x, acc);
            acc = fmaf(w.y, zz.y, acc);
            acc = fmaf(w.z, zz.z, acc);
            acc = fmaf(w.w, zz.w, acc);
        }
        ps[t] = acc;
    }
    __syncthreads();
    if (t < 512) h4[t] = fmaxf(ps[t] + ps[t + 512] + b4[t], 0.f);
    __syncthreads();
    {   // layer 5: 512 -> 512, 2-way k-split per output
        int o = t & 511, hf = t >> 9;
        float acc = 0.f;
        const float4* Wv = (const float4*)W5v;
        const float4* h44 = (const float4*)h4;
        #pragma unroll 4
        for (int kb = hf * 64; kb < hf * 64 + 64; ++kb) {
            float4 w = Wv[kb * 512 + o];
            float4 hh = h44[kb];
            acc = fmaf(w.x, hh.x, acc);
            acc = fmaf(w.y, hh.y, acc);
            acc = fmaf(w.z, hh.z, acc);
            acc = fmaf(w.w, hh.w, acc);
        }
        ps[t] = acc;
    }
    __syncthreads();
    if (t < 512) h5[t] = fmaxf(ps[t] + ps[t + 512] + b5[t], 0.f);
    __syncthreads();
    {   // layer 6: 512 -> 28 (32 lanes per output)
        int o = t >> 5, c = t & 31;
        if (o < 28) {
            float acc = 0.f;
            for (int k = c; k < 512; k += 32) acc = fmaf(W6[o * 512 + k], h5[k], acc);
            acc += __shfl_xor(acc, 1);
            acc += __shfl_xor(acc, 2);
            acc += __shfl_xor(acc, 4);
            acc += __shfl_xor(acc, 8);
            acc += __shfl_xor(acc, 16);
            if (c == 0) logits[o] = acc + b6[o];
        }
    }
    __syncthreads();
    if (t == 0) {
        float mx = -1e30f;
        for (int cc = 0; cc < 28; ++cc) mx = fmaxf(mx, logits[cc]);
        float se = 0.f;
        for (int cc = 0; cc < 28; ++cc) se += expf(logits[cc] - mx);
        red[0] = mx; red[1] = logf(se);
    }
    __syncthreads();
    if (t < 28) out[b * 28 + t] = logits[t] - red[0] - red[1];
}

extern "C" void kernel_launch(void* const* d_in, const int* in_sizes, int n_in,
                              void* d_out, int out_size, void* d_ws, size_t ws_size,
                              hipStream_t stream)
{
    const float* x   = (const float*)d_in[0];
    const float* qst = (const float*)d_in[1];
    const float* W0  = (const float*)d_in[2];
    const float* b0  = (const float*)d_in[3];
    const float* W1  = (const float*)d_in[4];
    const float* b1  = (const float*)d_in[5];
    const float* W2  = (const float*)d_in[6];
    const float* b2  = (const float*)d_in[7];
    const float* W3  = (const float*)d_in[8];
    const float* b3  = (const float*)d_in[9];
    const float* W4  = (const float*)d_in[10];
    const float* b4  = (const float*)d_in[11];
    const float* W5  = (const float*)d_in[12];
    const float* b5  = (const float*)d_in[13];
    const float* W6  = (const float*)d_in[14];
    const float* b6  = (const float*)d_in[15];
    float* out = (float*)d_out;

    char* ws = (char*)d_ws;
    unsigned short* Wp  = (unsigned short*)(ws);             // 1.5 MiB
    unsigned short* W0p = (unsigned short*)(ws + 1572864);   // 64 KiB
    float*          W4v = (float*)(ws + 1638400);            // 1.5 MiB
    float*          W5v = (float*)(ws + 3211264);            // 1 MiB
    float*          P   = (float*)(ws + 4259840);            // 4 MiB partials

    k_prep <<<NP_TOTAL / 256, 256, 0, stream>>>(W1, W2, W3, W0, W4, W5,
                                                Wp, W0p, W4v, W5v);
    k_fused<<<2048, 512, 0, stream>>>(x, Wp, W0p, b0, b1, b2, b3, P);
    k_tail <<<32, 1024, 0, stream>>>(P, qst, W4v, b4, W5v, b5, W6, b6, out);
}